// Round 9
// baseline (166.717 us; speedup 1.0000x reference)
//
#include <hip/hip_runtime.h>
#include <hip/hip_bf16.h>
#include <stdint.h>

typedef __attribute__((ext_vector_type(8))) __bf16 bf16x8;
typedef __attribute__((ext_vector_type(4))) float f32x4;

#define MFMA16(a,b,c) __builtin_amdgcn_mfma_f32_16x16x32_bf16((a),(b),(c),0,0,0)

#define BATCH 8
#define NPTS  2048

// ---- swizzles ----
__device__ __forceinline__ int swz128(int row, int col) {      // 64-col bf16 rows
    return row*128 + ((col*2) ^ (((row + (row >> 3)) & 7) << 4));
}
__device__ __forceinline__ int swz64(int row, int col) {       // 32-col bf16 rows
    return row*64 + ((col*2) ^ (((row + (row >> 2)) & 3) << 4));
}
__device__ __forceinline__ __bf16* p64(char* base, int row, int col) {
    return (__bf16*)(base + swz64(row, col));
}
__device__ __forceinline__ bf16x8 ld8_128(char* base, int row, int col) {
    return *(const bf16x8*)(base + swz128(row, col));
}
__device__ __forceinline__ bf16x8 ld8_64(char* base, int row, int col) {
    return *(const bf16x8*)p64(base, row, col);
}

// async global->LDS DMA, 16B per lane (pre-swizzled image -> linear copy)
__device__ __forceinline__ void dma16(const void* g, void* l) {
    __builtin_amdgcn_global_load_lds(
        (const __attribute__((address_space(1))) uint32_t*)g,
        (__attribute__((address_space(3))) uint32_t*)l, 16, 0, 0);
}

// ---- pre-pass: fused weight image in d_ws -----------------------------------
// bytes: [0,8192)     Wo^T [n=64][k=64] swz128
//        [8192,12288) W2^T [f=64][db=32 pad] swz64, W2 = Wv@Wo
//        [12288,14336) M^T [db=16][d=64] linear, M = SCALE*Wq@Wk^T
__global__ void prep_weights(const float* __restrict__ Wq, const float* __restrict__ Wk,
                             const float* __restrict__ Wv, const float* __restrict__ Wo,
                             __bf16* __restrict__ ws)
{
    int idx = blockIdx.x * 256 + threadIdx.x;   // 0..7167
    char* wsb = (char*)ws;
    if (idx < 4096) {
        int n = idx >> 6, k = idx & 63;
        *(__bf16*)(wsb + swz128(n, k)) = (__bf16)Wo[k*64 + n];
    } else if (idx < 6144) {
        int i = idx - 4096, f = i >> 5, db = i & 31;
        float acc = 0.f;
        if (db < 16) {
            for (int e = 0; e < 64; ++e) acc += Wv[db*64 + e] * Wo[e*64 + f];
        }
        *(__bf16*)(wsb + 8192 + swz64(f, db)) = (__bf16)acc;
    } else if (idx < 7168) {
        int i = idx - 6144, db = i >> 6, d = i & 63;
        float acc = 0.f;
        for (int e = 0; e < 64; ++e) acc += Wq[d*64 + e] * Wk[db*64 + e];
        *(__bf16*)(wsb + 12288 + db*128 + d*2) = (__bf16)(acc * 0.125f);
    }
}

__global__ void __launch_bounds__(256, 8) xattn_kernel(
    const float* __restrict__ voxel, const float* __restrict__ trans,
    const float* __restrict__ ws,     // prebuilt weight image (14 KB)
    const float* __restrict__ bo, const float* __restrict__ lng,
    const float* __restrict__ lnb, float* __restrict__ out)
{
    // LDS 16384 B -> 8 blocks/CU:
    // [0,8192) Wot | [8192,12288) W2t | [12288,16384) XPb [64][32] swz64
    __shared__ __align__(16) char lds[16384];
    char* Wot = lds;
    char* W2t = lds + 8192;
    char* XPb = lds + 12288;

    const int tid = threadIdx.x;
    const int bn  = blockIdx.x;
    const int w   = tid >> 6;     // wave 0..3; wave owns rows 16w..16w+15
    const int l   = tid & 63;
    const int l15 = l & 15;
    const int lq  = l >> 4;       // 0..3

    const f32x4 fzero = {0.f, 0.f, 0.f, 0.f};

    // ---------------- stage ---------------------------------------------------
    bf16x8 mf0, mf1, tfrag[2], ttf, xa0, xa1;
    {
        const char* wsb = (const char*)ws;
        // DMA Wo^T + W2^T images (12 KB = 12 segs of 1KB, 3 per wave)
        #pragma unroll
        for (int i = 0; i < 3; ++i) {
            int seg = i*4 + w;
            dma16(wsb + seg*1024 + l*16, lds + seg*1024);
        }
        // X fragments DIRECT from global (streamed once -> nontemporal):
        // lane: row 16w+l15, cols lq*8..+7 (xa0) and 32+lq*8..+7 (xa1)
        {
            const f32x4* gXr = (const f32x4*)(voxel + (size_t)bn*4096 + (16*w + l15)*64 + lq*8);
            f32x4 x0 = __builtin_nontemporal_load(gXr);
            f32x4 x1 = __builtin_nontemporal_load(gXr + 1);
            f32x4 x2 = __builtin_nontemporal_load(gXr + 8);     // +32 floats
            f32x4 x3 = __builtin_nontemporal_load(gXr + 9);
            #pragma unroll
            for (int i = 0; i < 4; ++i) {
                xa0[i]     = (__bf16)x0[i];
                xa0[i + 4] = (__bf16)x1[i];
                xa1[i]     = (__bf16)x2[i];
                xa1[i + 4] = (__bf16)x3[i];
            }
        }
        // M^T fragments (B of X@M): [col=db=l15][k=d]
        mf0 = *(const bf16x8*)(wsb + 12288 + l15*128 + lq*16);
        mf1 = *(const bf16x8*)(wsb + 12288 + l15*128 + 64 + lq*16);
        // T row fragments (B of S=XM@T^T): B[col=j=16tj+l15][k=db], db>=16 -> 0
        #pragma unroll
        for (int i = 0; i < 8; ++i) { tfrag[0][i] = (__bf16)0.f; tfrag[1][i] = (__bf16)0.f; }
        if (lq < 2) {
            #pragma unroll
            for (int tj = 0; tj < 2; ++tj) {
                const f32x4* gT = (const f32x4*)(trans + (size_t)bn*512 + (16*tj + l15)*16 + lq*8);
                f32x4 u0 = gT[0], u1 = gT[1];
                #pragma unroll
                for (int i = 0; i < 4; ++i) {
                    tfrag[tj][i]     = (__bf16)u0[i];
                    tfrag[tj][i + 4] = (__bf16)u1[i];
                }
            }
        }
        // T^T fragment (B of PT): B[col=db=l15][k=j=lq*8+i] = T[j][db]
        {
            const float* gT = trans + (size_t)bn * 512;
            float tt[8];
            #pragma unroll
            for (int i = 0; i < 8; ++i) tt[i] = gT[(lq*8 + i)*16 + l15];
            #pragma unroll
            for (int i = 0; i < 8; ++i) ttf[i] = (__bf16)tt[i];
        }
        // XPb pad: zero cols 16..31 of all 64 rows (K-pad for XM A-fragment)
        if (tid < 128) {
            f32x4 z = {0.f, 0.f, 0.f, 0.f};
            *(f32x4*)p64(XPb, tid >> 1, 16 + (tid & 1)*8) = z;
        }
    }
    __syncthreads();   // barrier 1 (drains DMA); ONLY barrier.
    // Post-barrier: every XPb access is to the wave's own 16 rows -> per-wave
    // LDS ordering (write->read FIFO) covers all hazards. (r4/r6-proven.)

    // ---------------- XM = X @ M  (SCALE folded into M) ----------------------
    {
        f32x4 xm = MFMA16(xa0, mf0, fzero);
        xm = MFMA16(xa1, mf1, xm);
        #pragma unroll
        for (int r = 0; r < 4; ++r)
            *p64(XPb, 16*w + lq*4 + r, l15) = (__bf16)xm[r];
    }
    // ---------------- S = XM @ T^T, softmax -> P -----------------------------
    {
        bf16x8 xma = ld8_64(XPb, 16*w + l15, lq*8);    // k 16..31 = staged zeros
        f32x4 s0 = MFMA16(xma, tfrag[0], fzero);
        f32x4 s1 = MFMA16(xma, tfrag[1], fzero);
        // logits pre-scaled; |logit| < ~2 -> direct exp safe in f32
        #pragma unroll
        for (int r = 0; r < 4; ++r) {
            float p0 = __expf(s0[r]);
            float p1 = __expf(s1[r]);
            float su = p0 + p1;
            #pragma unroll
            for (int off = 1; off < 16; off <<= 1) su += __shfl_xor(su, off);
            float inv = __builtin_amdgcn_rcpf(su);
            *p64(XPb, 16*w + lq*4 + r, l15)      = (__bf16)(p0 * inv);
            *p64(XPb, 16*w + lq*4 + r, 16 + l15) = (__bf16)(p1 * inv);
        }
    }
    // ---------------- PT = P @ T  [64 x 16(db)] ------------------------------
    {
        bf16x8 ap = ld8_64(XPb, 16*w + l15, lq*8);     // P rows, k=j full 32
        f32x4 pt = MFMA16(ap, ttf, fzero);
        #pragma unroll
        for (int r = 0; r < 4; ++r) {                  // write PT + re-zero pad
            *p64(XPb, 16*w + lq*4 + r, l15)      = (__bf16)pt[r];
            *p64(XPb, 16*w + lq*4 + r, 16 + l15) = (__bf16)0.f;
        }
    }
    // ---------------- Y^T tiles: Y = PT@W2 + X@Wo + bo; LN; float4 store -----
    // Swapped-operand MFMA: D = A(W-frag) . B(X-frag) => lane holds
    // Y[16w+l15][16t+lq*4+r] -- one row, 4 consecutive cols per tile t.
    {
        bf16x8 pta = ld8_64(XPb, 16*w + l15, lq*8);
        const int colbase = lq*4;
        f32x4 y[4];
        #pragma unroll
        for (int t = 0; t < 4; ++t) {
            bf16x8 a0  = ld8_128(Wot, 16*t + l15, lq*8);       // A: Wo^T rows
            bf16x8 a1  = ld8_128(Wot, 16*t + l15, 32 + lq*8);
            bf16x8 w2a = ld8_64 (W2t, 16*t + l15, lq*8);       // A: W2^T rows
            y[t] = MFMA16(a0, xa0, fzero);
            y[t] = MFMA16(a1, xa1, y[t]);
            y[t] = MFMA16(w2a, pta, y[t]);
        }
        float s1 = 0.f, s2 = 0.f;
        #pragma unroll
        for (int t = 0; t < 4; ++t) {
            f32x4 bov = *(const f32x4*)(bo + 16*t + colbase);
            #pragma unroll
            for (int r = 0; r < 4; ++r) {
                y[t][r] += bov[r];
                s1 += y[t][r]; s2 += y[t][r]*y[t][r];
            }
        }
        // row stats: partners are the other lq-groups (same l15) -> 2 steps
        s1 += __shfl_xor(s1, 16); s2 += __shfl_xor(s2, 16);
        s1 += __shfl_xor(s1, 32); s2 += __shfl_xor(s2, 32);
        float mu  = s1 * 0.015625f;
        float var = s2 * 0.015625f - mu * mu;
        float rs  = rsqrtf(var + 1e-5f);
        float* grow = out + (size_t)bn*4096 + (16*w + l15)*64;
        #pragma unroll
        for (int t = 0; t < 4; ++t) {
            f32x4 gv = *(const f32x4*)(lng + 16*t + colbase);
            f32x4 bv = *(const f32x4*)(lnb + 16*t + colbase);
            f32x4 o4;
            #pragma unroll
            for (int r = 0; r < 4; ++r)
                o4[r] = (y[t][r] - mu) * rs * gv[r] + bv[r];
            __builtin_nontemporal_store(o4, (f32x4*)(grow + 16*t + colbase));
        }
    }
}

extern "C" void kernel_launch(void* const* d_in, const int* in_sizes, int n_in,
                              void* d_out, int out_size, void* d_ws, size_t ws_size,
                              hipStream_t stream) {
    const float* voxel = (const float*)d_in[0];
    const float* trans = (const float*)d_in[1];
    const float* Wq = (const float*)d_in[2];
    const float* Wk = (const float*)d_in[3];
    const float* Wv = (const float*)d_in[4];
    const float* Wo = (const float*)d_in[5];
    const float* bo = (const float*)d_in[6];
    const float* g  = (const float*)d_in[7];
    const float* b  = (const float*)d_in[8];
    float* o = (float*)d_out;

    prep_weights<<<dim3(28), dim3(256), 0, stream>>>(Wq, Wk, Wv, Wo, (__bf16*)d_ws);
    xattn_kernel<<<dim3(BATCH * NPTS), dim3(256), 0, stream>>>(
        voxel, trans, (const float*)d_ws, bo, g, b, o);
}

// Round 11
// 151.929 us; speedup vs baseline: 1.0973x; 1.0973x over previous
//
#include <hip/hip_runtime.h>
#include <hip/hip_bf16.h>
#include <stdint.h>

typedef __attribute__((ext_vector_type(8))) __bf16 bf16x8;
typedef __attribute__((ext_vector_type(4))) float f32x4;
typedef __attribute__((ext_vector_type(4))) unsigned int u32x4;

#define MFMA16(a,b,c) __builtin_amdgcn_mfma_f32_16x16x32_bf16((a),(b),(c),0,0,0)

#define BATCH 8
#define NPTS  2048

// ---- swizzles ----
__device__ __forceinline__ int swz128(int row, int col) {      // 64-col bf16 rows
    return row*128 + ((col*2) ^ (((row + (row >> 3)) & 7) << 4));
}
__device__ __forceinline__ int swz64(int row, int col) {       // 32-col bf16 rows
    return row*64 + ((col*2) ^ (((row + (row >> 2)) & 3) << 4));
}
__device__ __forceinline__ __bf16* p64(char* base, int row, int col) {
    return (__bf16*)(base + swz64(row, col));
}
__device__ __forceinline__ bf16x8 ld8_128(char* base, int row, int col) {
    return *(const bf16x8*)(base + swz128(row, col));
}
__device__ __forceinline__ bf16x8 ld8_64(char* base, int row, int col) {
    return *(const bf16x8*)p64(base, row, col);
}

// ---- pre-pass: fused weight image in d_ws -----------------------------------
// bytes: [0,8192)     Wo^T [n=64][k=64] swz128
//        [8192,12288) W2^T [f=64][db=32 pad] swz64, W2 = Wv@Wo
//        [12288,14336) M^T [db=16][d=64] linear, M = SCALE*Wq@Wk^T
__global__ void prep_weights(const float* __restrict__ Wq, const float* __restrict__ Wk,
                             const float* __restrict__ Wv, const float* __restrict__ Wo,
                             __bf16* __restrict__ ws)
{
    int idx = blockIdx.x * 256 + threadIdx.x;   // 0..7167
    char* wsb = (char*)ws;
    if (idx < 4096) {
        int n = idx >> 6, k = idx & 63;
        *(__bf16*)(wsb + swz128(n, k)) = (__bf16)Wo[k*64 + n];
    } else if (idx < 6144) {
        int i = idx - 4096, f = i >> 5, db = i & 31;
        float acc = 0.f;
        if (db < 16) {
            for (int e = 0; e < 64; ++e) acc += Wv[db*64 + e] * Wo[e*64 + f];
        }
        *(__bf16*)(wsb + 8192 + swz64(f, db)) = (__bf16)acc;
    } else if (idx < 7168) {
        int i = idx - 6144, db = i >> 6, d = i & 63;
        float acc = 0.f;
        for (int e = 0; e < 64; ++e) acc += Wq[d*64 + e] * Wk[db*64 + e];
        *(__bf16*)(wsb + 12288 + db*128 + d*2) = (__bf16)(acc * 0.125f);
    }
}

__global__ void __launch_bounds__(256, 6) xattn_kernel(
    const float* __restrict__ voxel, const float* __restrict__ trans,
    const float* __restrict__ ws,     // prebuilt weight image (14 KB)
    const float* __restrict__ bo, const float* __restrict__ lng,
    const float* __restrict__ lnb, float* __restrict__ out)
{
    // LDS 16384 B:
    // [0,8192) Wot | [8192,12288) W2t | [12288,16384) XPb [64][32] swz64
    __shared__ __align__(16) char lds[16384];
    char* Wot = lds;
    char* W2t = lds + 8192;
    char* XPb = lds + 12288;

    const int tid = threadIdx.x;
    const int bn  = blockIdx.x;
    const int w   = tid >> 6;     // wave 0..3; wave owns rows 16w..16w+15
    const int l   = tid & 63;
    const int l15 = l & 15;
    const int lq  = l >> 4;       // 0..3

    const f32x4 fzero = {0.f, 0.f, 0.f, 0.f};

    // ---------------- stage ---------------------------------------------------
    bf16x8 mf0, mf1, tfrag[2], ttf, xa0, xa1;
    {
        const char* wsb = (const char*)ws;
        // REG-STAGED weight image copy (12 KB): 3 sweeps of 4 KB.
        // Plain loads + ds_write_b128 -- compiler-tracked lgkmcnt, provably
        // drained at the barrier (replaces global_load_lds; r10 post-mortem).
        u32x4 wimg[3];
        #pragma unroll
        for (int i = 0; i < 3; ++i)
            wimg[i] = *(const u32x4*)(wsb + i*4096 + tid*16);
        #pragma unroll
        for (int i = 0; i < 3; ++i)
            *(u32x4*)(lds + i*4096 + tid*16) = wimg[i];
        // X fragments DIRECT from global:
        // lane: row 16w+l15, cols lq*8..+7 (xa0) and 32+lq*8..+7 (xa1)
        {
            const f32x4* gXr = (const f32x4*)(voxel + (size_t)bn*4096 + (16*w + l15)*64 + lq*8);
            f32x4 x0 = gXr[0];
            f32x4 x1 = gXr[1];
            f32x4 x2 = gXr[8];     // +32 floats
            f32x4 x3 = gXr[9];
            #pragma unroll
            for (int i = 0; i < 4; ++i) {
                xa0[i]     = (__bf16)x0[i];
                xa0[i + 4] = (__bf16)x1[i];
                xa1[i]     = (__bf16)x2[i];
                xa1[i + 4] = (__bf16)x3[i];
            }
        }
        // M^T fragments (B of X@M): [col=db=l15][k=d]
        mf0 = *(const bf16x8*)(wsb + 12288 + l15*128 + lq*16);
        mf1 = *(const bf16x8*)(wsb + 12288 + l15*128 + 64 + lq*16);
        // T row fragments (B of S=XM@T^T): B[col=j=16tj+l15][k=db], db>=16 -> 0
        #pragma unroll
        for (int i = 0; i < 8; ++i) { tfrag[0][i] = (__bf16)0.f; tfrag[1][i] = (__bf16)0.f; }
        if (lq < 2) {
            #pragma unroll
            for (int tj = 0; tj < 2; ++tj) {
                const f32x4* gT = (const f32x4*)(trans + (size_t)bn*512 + (16*tj + l15)*16 + lq*8);
                f32x4 u0 = gT[0], u1 = gT[1];
                #pragma unroll
                for (int i = 0; i < 4; ++i) {
                    tfrag[tj][i]     = (__bf16)u0[i];
                    tfrag[tj][i + 4] = (__bf16)u1[i];
                }
            }
        }
        // T^T fragment (B of PT): B[col=db=l15][k=j=lq*8+i] = T[j][db]
        {
            const float* gT = trans + (size_t)bn * 512;
            float tt[8];
            #pragma unroll
            for (int i = 0; i < 8; ++i) tt[i] = gT[(lq*8 + i)*16 + l15];
            #pragma unroll
            for (int i = 0; i < 8; ++i) ttf[i] = (__bf16)tt[i];
        }
        // XPb pad: zero cols 16..31 of all 64 rows (K-pad for XM A-fragment)
        if (tid < 128) {
            f32x4 z = {0.f, 0.f, 0.f, 0.f};
            *(f32x4*)p64(XPb, tid >> 1, 16 + (tid & 1)*8) = z;
        }
    }
    // explicit drain (belt and suspenders -- r10 post-mortem)
    asm volatile("s_waitcnt vmcnt(0) lgkmcnt(0)" ::: "memory");
    __syncthreads();   // barrier 1; ONLY barrier.
    // Post-barrier: every XPb access is to the wave's own 16 rows -> per-wave
    // LDS ordering (write->read FIFO) covers all hazards. (r4/r6-proven.)

    // ---------------- XM = X @ M  (SCALE folded into M) ----------------------
    {
        f32x4 xm = MFMA16(xa0, mf0, fzero);
        xm = MFMA16(xa1, mf1, xm);
        #pragma unroll
        for (int r = 0; r < 4; ++r)
            *p64(XPb, 16*w + lq*4 + r, l15) = (__bf16)xm[r];
    }
    // ---------------- S = XM @ T^T, softmax -> P -----------------------------
    {
        bf16x8 xma = ld8_64(XPb, 16*w + l15, lq*8);    // k 16..31 = staged zeros
        f32x4 s0 = MFMA16(xma, tfrag[0], fzero);
        f32x4 s1 = MFMA16(xma, tfrag[1], fzero);
        // logits pre-scaled; |logit| < ~2 -> direct exp safe in f32
        #pragma unroll
        for (int r = 0; r < 4; ++r) {
            float p0 = __expf(s0[r]);
            float p1 = __expf(s1[r]);
            float su = p0 + p1;
            #pragma unroll
            for (int off = 1; off < 16; off <<= 1) su += __shfl_xor(su, off);
            float inv = __builtin_amdgcn_rcpf(su);
            *p64(XPb, 16*w + lq*4 + r, l15)      = (__bf16)(p0 * inv);
            *p64(XPb, 16*w + lq*4 + r, 16 + l15) = (__bf16)(p1 * inv);
        }
    }
    // ---------------- PT = P @ T  [64 x 16(db)] ------------------------------
    {
        bf16x8 ap = ld8_64(XPb, 16*w + l15, lq*8);     // P rows, k=j full 32
        f32x4 pt = MFMA16(ap, ttf, fzero);
        #pragma unroll
        for (int r = 0; r < 4; ++r) {                  // write PT + re-zero pad
            *p64(XPb, 16*w + lq*4 + r, l15)      = (__bf16)pt[r];
            *p64(XPb, 16*w + lq*4 + r, 16 + l15) = (__bf16)0.f;
        }
    }
    // ---------------- Y^T tiles: Y = PT@W2 + X@Wo + bo; LN; f32x4 store ------
    // Swapped-operand MFMA: D = A(W-frag) . B(X-frag) => lane holds
    // Y[16w+l15][16t+lq*4+r] -- one row, 4 consecutive cols per tile t.
    {
        bf16x8 pta = ld8_64(XPb, 16*w + l15, lq*8);
        const int colbase = lq*4;
        f32x4 y[4];
        #pragma unroll
        for (int t = 0; t < 4; ++t) {
            bf16x8 a0  = ld8_128(Wot, 16*t + l15, lq*8);       // A: Wo^T rows
            bf16x8 a1  = ld8_128(Wot, 16*t + l15, 32 + lq*8);
            bf16x8 w2a = ld8_64 (W2t, 16*t + l15, lq*8);       // A: W2^T rows
            y[t] = MFMA16(a0, xa0, fzero);
            y[t] = MFMA16(a1, xa1, y[t]);
            y[t] = MFMA16(w2a, pta, y[t]);
        }
        float s1 = 0.f, s2 = 0.f;
        #pragma unroll
        for (int t = 0; t < 4; ++t) {
            f32x4 bov = *(const f32x4*)(bo + 16*t + colbase);
            #pragma unroll
            for (int r = 0; r < 4; ++r) {
                y[t][r] += bov[r];
                s1 += y[t][r]; s2 += y[t][r]*y[t][r];
            }
        }
        // row stats: partners are the other lq-groups (same l15) -> 2 steps
        s1 += __shfl_xor(s1, 16); s2 += __shfl_xor(s2, 16);
        s1 += __shfl_xor(s1, 32); s2 += __shfl_xor(s2, 32);
        float mu  = s1 * 0.015625f;
        float var = s2 * 0.015625f - mu * mu;
        float rs  = rsqrtf(var + 1e-5f);
        float* grow = out + (size_t)bn*4096 + (16*w + l15)*64;
        #pragma unroll
        for (int t = 0; t < 4; ++t) {
            f32x4 gv = *(const f32x4*)(lng + 16*t + colbase);
            f32x4 bv = *(const f32x4*)(lnb + 16*t + colbase);
            f32x4 o4;
            #pragma unroll
            for (int r = 0; r < 4; ++r)
                o4[r] = (y[t][r] - mu) * rs * gv[r] + bv[r];
            *(f32x4*)(grow + 16*t + colbase) = o4;
        }
    }
}

extern "C" void kernel_launch(void* const* d_in, const int* in_sizes, int n_in,
                              void* d_out, int out_size, void* d_ws, size_t ws_size,
                              hipStream_t stream) {
    const float* voxel = (const float*)d_in[0];
    const float* trans = (const float*)d_in[1];
    const float* Wq = (const float*)d_in[2];
    const float* Wk = (const float*)d_in[3];
    const float* Wv = (const float*)d_in[4];
    const float* Wo = (const float*)d_in[5];
    const float* bo = (const float*)d_in[6];
    const float* g  = (const float*)d_in[7];
    const float* b  = (const float*)d_in[8];
    float* o = (float*)d_out;

    prep_weights<<<dim3(28), dim3(256), 0, stream>>>(Wq, Wk, Wv, Wo, (__bf16*)d_ws);
    xattn_kernel<<<dim3(BATCH * NPTS), dim3(256), 0, stream>>>(
        voxel, trans, (const float*)d_ws, bo, g, b, o);
}

// Round 12
// 130.656 us; speedup vs baseline: 1.2760x; 1.1628x over previous
//
#include <hip/hip_runtime.h>
#include <hip/hip_bf16.h>
#include <stdint.h>

typedef __attribute__((ext_vector_type(8))) __bf16 bf16x8;
typedef __attribute__((ext_vector_type(4))) __bf16 bf16x4;
typedef __attribute__((ext_vector_type(4))) float f32x4;
typedef __attribute__((ext_vector_type(4))) unsigned int u32x4;

#define MFMA16(a,b,c) __builtin_amdgcn_mfma_f32_16x16x32_bf16((a),(b),(c),0,0,0)

#define BATCH 8
#define NPTS  2048

// ---- swizzles ----
__device__ __forceinline__ int swz128(int row, int col) {      // 64-col bf16 rows
    return row*128 + ((col*2) ^ (((row + (row >> 3)) & 7) << 4));
}
__device__ __forceinline__ int swz64(int row, int col) {       // 32-col bf16 rows
    return row*64 + ((col*2) ^ (((row + (row >> 2)) & 3) << 4));
}
__device__ __forceinline__ __bf16* p128(char* base, int row, int col) {
    return (__bf16*)(base + swz128(row, col));
}
__device__ __forceinline__ __bf16* p64(char* base, int row, int col) {
    return (__bf16*)(base + swz64(row, col));
}
__device__ __forceinline__ bf16x8 ld8_128(char* base, int row, int col) {
    return *(const bf16x8*)p128(base, row, col);
}
__device__ __forceinline__ bf16x8 ld8_64(char* base, int row, int col) {
    return *(const bf16x8*)p64(base, row, col);
}

// ---- pre-pass: fused weight image in d_ws -----------------------------------
// bytes: [0,8192)     Wo^T [n=64][k=64] swz128  (B of X@Wo)
//        [8192,12288) W2^T [f=64][db=32 pad] swz64, W2 = Wv@Wo  (B of PT@W2)
//        [12288,14336) M^T [db=16][d=64] linear, M = SCALE*Wq@Wk^T (B of X@M)
__global__ void prep_weights(const float* __restrict__ Wq, const float* __restrict__ Wk,
                             const float* __restrict__ Wv, const float* __restrict__ Wo,
                             __bf16* __restrict__ ws)
{
    int idx = blockIdx.x * 256 + threadIdx.x;   // 0..7167
    char* wsb = (char*)ws;
    if (idx < 4096) {
        int n = idx >> 6, k = idx & 63;
        *(__bf16*)(wsb + swz128(n, k)) = (__bf16)Wo[k*64 + n];
    } else if (idx < 6144) {
        int i = idx - 4096, f = i >> 5, db = i & 31;
        float acc = 0.f;
        if (db < 16) {
            for (int e = 0; e < 64; ++e) acc += Wv[db*64 + e] * Wo[e*64 + f];
        }
        *(__bf16*)(wsb + 8192 + swz64(f, db)) = (__bf16)acc;
    } else if (idx < 7168) {
        int i = idx - 6144, db = i >> 6, d = i & 63;
        float acc = 0.f;
        for (int e = 0; e < 64; ++e) acc += Wq[d*64 + e] * Wk[db*64 + e];
        *(__bf16*)(wsb + 12288 + db*128 + d*2) = (__bf16)(acc * 0.125f);
    }
}

__global__ void __launch_bounds__(256, 6) xattn_kernel(
    const float* __restrict__ voxel, const float* __restrict__ trans,
    const float* __restrict__ ws,     // prebuilt weight image (14 KB)
    const float* __restrict__ bo, const float* __restrict__ lng,
    const float* __restrict__ lnb, float* __restrict__ out)
{
    // LDS 24576 B (6 blocks/CU = 147456 <= 163840). NO OVERLAPS:
    // [0,8192) Wot | [8192,12288) W2t | [12288,20480) Xb
    // [20480,24576) XPb [64][32] swz64 = 4096 B (XM -> P -> PT scratch)
    __shared__ __align__(16) char lds[24576];
    char* Wot = lds;
    char* W2t = lds + 8192;
    char* Xb  = lds + 12288;
    char* XPb = lds + 20480;

    const int tid = threadIdx.x;
    const int bn  = blockIdx.x;
    const int w   = tid >> 6;     // wave 0..3; wave owns rows 16w..16w+15
    const int l   = tid & 63;
    const int l15 = l & 15;
    const int lq  = l >> 4;       // 0..3

    const f32x4 fzero = {0.f, 0.f, 0.f, 0.f};

    // ---------------- stage ---------------------------------------------------
    bf16x8 mf0, mf1, tfrag[2], ttf;
    {
        const char* wsb = (const char*)ws;
        // REG-STAGED weight image copy (12 KB = 3 sweeps of 4 KB).
        // Plain loads + ds_write_b128: compiler-tracked lgkmcnt, provably
        // drained at the barrier (replaces global_load_lds; r10 post-mortem).
        u32x4 wimg[3];
        #pragma unroll
        for (int i = 0; i < 3; ++i)
            wimg[i] = *(const u32x4*)(wsb + i*4096 + tid*16);
        #pragma unroll
        for (int i = 0; i < 3; ++i)
            *(u32x4*)(lds + i*4096 + tid*16) = wimg[i];
        // M^T fragments (B of X@M): [col=db=l15][k=d]
        mf0 = *(const bf16x8*)(wsb + 12288 + l15*128 + lq*16);
        mf1 = *(const bf16x8*)(wsb + 12288 + l15*128 + 64 + lq*16);
        // T row fragments (B of S=XM@T^T): B[col=j=16tj+l15][k=db], db>=16 -> 0
        #pragma unroll
        for (int i = 0; i < 8; ++i) { tfrag[0][i] = (__bf16)0.f; tfrag[1][i] = (__bf16)0.f; }
        if (lq < 2) {
            #pragma unroll
            for (int tj = 0; tj < 2; ++tj) {
                const f32x4* gT = (const f32x4*)(trans + (size_t)bn*512 + (16*tj + l15)*16 + lq*8);
                f32x4 u0 = gT[0], u1 = gT[1];
                #pragma unroll
                for (int i = 0; i < 4; ++i) {
                    tfrag[tj][i]     = (__bf16)u0[i];
                    tfrag[tj][i + 4] = (__bf16)u1[i];
                }
            }
        }
        // T^T fragment (B of PT): B[col=db=l15][k=j=lq*8+i] = T[j][db]
        {
            const float* gT = trans + (size_t)bn * 512;
            float tt[8];
            #pragma unroll
            for (int i = 0; i < 8; ++i) tt[i] = gT[(lq*8 + i)*16 + l15];
            #pragma unroll
            for (int i = 0; i < 8; ++i) ttf[i] = (__bf16)tt[i];
        }
        // X: [64][64] f32 coalesced -> Xb bf16 swz128
        const f32x4* gX = (const f32x4*)(voxel + (size_t)bn * 4096);
        #pragma unroll
        for (int j = 0; j < 4; ++j) {
            f32x4 v = gX[j*256 + tid];
            int gi  = j*256 + tid;
            int row = gi >> 4;
            int col = (gi & 15) * 4;
            bf16x4 h;
            #pragma unroll
            for (int i = 0; i < 4; ++i) h[i] = (__bf16)v[i];
            *(bf16x4*)p128(Xb, row, col) = h;
        }
        // XPb pad: zero cols 16..31 of all 64 rows (K-pad for XM A-fragment)
        if (tid < 128) {
            f32x4 z = {0.f, 0.f, 0.f, 0.f};
            *(f32x4*)p64(XPb, tid >> 1, 16 + (tid & 1)*8) = z;
        }
    }
    // explicit drain (belt and suspenders -- r10 post-mortem)
    asm volatile("s_waitcnt vmcnt(0) lgkmcnt(0)" ::: "memory");
    __syncthreads();   // barrier 1; ONLY barrier.
    // Post-barrier: every XPb access is to the wave's own 16 rows -> per-wave
    // LDS ordering (write->read FIFO) covers all hazards. (r4/r6-proven.)

    bf16x8 xa0 = ld8_128(Xb, 16*w + l15, lq*8);
    bf16x8 xa1 = ld8_128(Xb, 16*w + l15, 32 + lq*8);

    // ---------------- XM = X @ M  (SCALE folded into M) ----------------------
    {
        f32x4 xm = MFMA16(xa0, mf0, fzero);
        xm = MFMA16(xa1, mf1, xm);
        #pragma unroll
        for (int r = 0; r < 4; ++r)
            *p64(XPb, 16*w + lq*4 + r, l15) = (__bf16)xm[r];
    }
    // ---------------- S = XM @ T^T, softmax -> P -----------------------------
    {
        bf16x8 xma = ld8_64(XPb, 16*w + l15, lq*8);    // k 16..31 = staged zeros
        f32x4 s0 = MFMA16(xma, tfrag[0], fzero);
        f32x4 s1 = MFMA16(xma, tfrag[1], fzero);
        // logits pre-scaled; |logit| < ~2 -> direct exp safe in f32
        #pragma unroll
        for (int r = 0; r < 4; ++r) {
            float p0 = __expf(s0[r]);
            float p1 = __expf(s1[r]);
            float su = p0 + p1;
            #pragma unroll
            for (int off = 1; off < 16; off <<= 1) su += __shfl_xor(su, off);
            float inv = __builtin_amdgcn_rcpf(su);
            *p64(XPb, 16*w + lq*4 + r, l15)      = (__bf16)(p0 * inv);
            *p64(XPb, 16*w + lq*4 + r, 16 + l15) = (__bf16)(p1 * inv);
        }
    }
    // ---------------- PT = P @ T  [64 x 16(db)] ------------------------------
    {
        bf16x8 ap = ld8_64(XPb, 16*w + l15, lq*8);     // P rows, k=j full 32
        f32x4 pt = MFMA16(ap, ttf, fzero);
        #pragma unroll
        for (int r = 0; r < 4; ++r) {                  // write PT + re-zero pad
            *p64(XPb, 16*w + lq*4 + r, l15)      = (__bf16)pt[r];
            *p64(XPb, 16*w + lq*4 + r, 16 + l15) = (__bf16)0.f;
        }
    }
    // ---------------- Y = PT@W2 + X@Wo + bo; LayerNorm; store ----------------
    {
        bf16x8 pta = ld8_64(XPb, 16*w + l15, lq*8);
        float bo4[4], g4[4], b4[4];
        #pragma unroll
        for (int t = 0; t < 4; ++t) {
            int c = 16*t + l15;
            bo4[t] = bo[c]; g4[t] = lng[c]; b4[t] = lnb[c];
        }
        f32x4 y[4];
        #pragma unroll
        for (int t = 0; t < 4; ++t) {
            bf16x8 b0  = ld8_128(Wot, 16*t + l15, lq*8);
            bf16x8 b1  = ld8_128(Wot, 16*t + l15, 32 + lq*8);
            bf16x8 w2b = ld8_64 (W2t, 16*t + l15, lq*8);
            y[t] = MFMA16(xa0, b0, fzero);
            y[t] = MFMA16(xa1, b1, y[t]);
            y[t] = MFMA16(pta, w2b, y[t]);
        }
        float* gout = out + (size_t)bn * 4096;
        #pragma unroll
        for (int r = 0; r < 4; ++r) {
            float v0 = y[0][r] + bo4[0];
            float v1 = y[1][r] + bo4[1];
            float v2 = y[2][r] + bo4[2];
            float v3 = y[3][r] + bo4[3];
            float s1 = v0 + v1 + v2 + v3;
            float s2 = v0*v0 + v1*v1 + v2*v2 + v3*v3;
            #pragma unroll
            for (int off = 1; off < 16; off <<= 1) {
                s1 += __shfl_xor(s1, off);
                s2 += __shfl_xor(s2, off);
            }
            float mu  = s1 * 0.015625f;
            float var = s2 * 0.015625f - mu * mu;
            float rs  = rsqrtf(var + 1e-5f);
            int row = 16*w + lq*4 + r;
            gout[row*64 +      l15] = (v0 - mu) * rs * g4[0] + b4[0];
            gout[row*64 + 16 + l15] = (v1 - mu) * rs * g4[1] + b4[1];
            gout[row*64 + 32 + l15] = (v2 - mu) * rs * g4[2] + b4[2];
            gout[row*64 + 48 + l15] = (v3 - mu) * rs * g4[3] + b4[3];
        }
    }
}

extern "C" void kernel_launch(void* const* d_in, const int* in_sizes, int n_in,
                              void* d_out, int out_size, void* d_ws, size_t ws_size,
                              hipStream_t stream) {
    const float* voxel = (const float*)d_in[0];
    const float* trans = (const float*)d_in[1];
    const float* Wq = (const float*)d_in[2];
    const float* Wk = (const float*)d_in[3];
    const float* Wv = (const float*)d_in[4];
    const float* Wo = (const float*)d_in[5];
    const float* bo = (const float*)d_in[6];
    const float* g  = (const float*)d_in[7];
    const float* b  = (const float*)d_in[8];
    float* o = (float*)d_out;

    prep_weights<<<dim3(28), dim3(256), 0, stream>>>(Wq, Wk, Wv, Wo, (__bf16*)d_ws);
    xattn_kernel<<<dim3(BATCH * NPTS), dim3(256), 0, stream>>>(
        voxel, trans, (const float*)d_ws, bo, g, b, o);
}